// Round 8
// baseline (357.173 us; speedup 1.0000x reference)
//
#include <hip/hip_runtime.h>

// LSTMClassifier: B=4096, T=128, I=32, H=64, 2-layer LSTM + MLP head.
// Round 7b (compile fix): TWO independent blocks per CU (decorrelated
// barriers = the r3/r6 phase-lock fix). 512 blocks x 512 threads, 8 batch
// rows per block; waves 0-3 layer 0 at step k, waves 4-7 layer 1 at step k-1;
// double-buffered LDS h-state; one lgkm-only barrier per step. MFMA computes
// gates TRANSPOSED (D[gatecol][batchrow], W as A-operand, h as B-operand) so
// the 8 valid rows sit on the lane&15 axis: one ds_swizzle(xor 8) + cndmask
// redistributes to 2 valid cells/lane (eltwise issue stays invariant; only
// MFMA pays the M=16 padding). __launch_bounds__(512,4) => 4 waves/SIMD from
// two blocks. f16 MFMA operands, fp32 state; 7 transcendentals/cell.

#define TT 128

typedef _Float16 half8 __attribute__((ext_vector_type(8)));
typedef _Float16 half2v __attribute__((ext_vector_type(2)));
typedef float floatx4 __attribute__((ext_vector_type(4)));

#define LOG2E 1.4426950408889634f

// Workgroup barrier waiting only on LDS ops (lgkmcnt), not vmem: in-flight
// global x lookahead loads cross the barrier freely (consumed register-side
// with compiler-inserted vmcnt waits).
__device__ __forceinline__ void bar_lds() {
    asm volatile("s_waitcnt lgkmcnt(0)\n\ts_barrier" ::: "memory");
}

// Pull a float from lane^8 (BitMode xor=8, and=0x1F -> stays in 32-lane half).
__device__ __forceinline__ float swz8(float v) {
    int i = __builtin_bit_cast(int, v);
    i = __builtin_amdgcn_ds_swizzle(i, 0x201F);
    return __builtin_bit_cast(float, i);
}

// Pack two f32 -> f16x2 (RTZ) as our half2v type.
__device__ __forceinline__ half2v pk16(float a, float b) {
    return __builtin_bit_cast(half2v, __builtin_amdgcn_cvt_pkrtz(a, b));
}

// Load 8 consecutive fp32 of row n and convert to an f16 MFMA fragment.
// Serves as the W A-operand frag: lane holds W[tile+lr][8q..8q+8).
__device__ __forceinline__ half8 load_w_frag(const float* __restrict__ W, int n, int K, int k0) {
    const float* p = W + (size_t)n * K + k0;
    float4 a = *(const float4*)p;
    float4 b = *(const float4*)(p + 4);
    half8 h;
    h[0] = (_Float16)a.x; h[1] = (_Float16)a.y; h[2] = (_Float16)a.z; h[3] = (_Float16)a.w;
    h[4] = (_Float16)b.x; h[5] = (_Float16)b.y; h[6] = (_Float16)b.z; h[7] = (_Float16)b.w;
    return h;
}

__device__ __forceinline__ half8 cvt_frag(float4 a, float4 b) {
    half8 h;
    h[0] = (_Float16)a.x; h[1] = (_Float16)a.y; h[2] = (_Float16)a.z; h[3] = (_Float16)a.w;
    h[4] = (_Float16)b.x; h[5] = (_Float16)b.y; h[6] = (_Float16)b.z; h[7] = (_Float16)b.w;
    return h;
}

// LSTM cell eltwise, 7 transcendentals (5 exp + 2 rcp), HW-validated r5/r6:
// sig(f) and sig(i)*tanh(g) share one rcp; clamps at +-12 keep products
// fp32-safe with tail error < 7e-6.
__device__ __forceinline__ void cell_update(float gi, float gf, float gg, float go,
                                            float& c, float& h) {
    gi = fminf(fmaxf(gi, -12.f), 12.f);
    gf = fminf(fmaxf(gf, -12.f), 12.f);
    gg = fminf(fmaxf(gg, -12.f), 12.f);
    float u  = __builtin_amdgcn_exp2f(gg * (2.f * LOG2E));
    float vi = __builtin_amdgcn_exp2f(-gi * LOG2E);
    float vf = __builtin_amdgcn_exp2f(-gf * LOG2E);
    float u1 = u + 1.f;
    float D1 = 1.f + vf;
    float D2 = fmaf(vi, u1, u1);
    float R  = __builtin_amdgcn_rcpf(D1 * D2);
    float sigf = R * D2;
    float sit  = (u - 1.f) * (R * D1);
    c = fmaf(sigf, c, sit);
    float cc = fminf(fmaxf(c, -12.f), 12.f);
    float w  = __builtin_amdgcn_exp2f(cc * (2.f * LOG2E));
    float vo = __builtin_amdgcn_exp2f(-go * LOG2E);
    float w1 = w + 1.f;
    float den = fmaf(vo, w1, w1);
    h = (w - 1.f) * __builtin_amdgcn_rcpf(den);
}

__global__ __launch_bounds__(512, 4) void lstm_fused(
    const float* __restrict__ x,
    const float* __restrict__ Wih0, const float* __restrict__ Whh0,
    const float* __restrict__ bih0, const float* __restrict__ bhh0,
    const float* __restrict__ Wih1, const float* __restrict__ Whh1,
    const float* __restrict__ bih1, const float* __restrict__ bhh1,
    const float* __restrict__ Wc1, const float* __restrict__ bc1,
    const float* __restrict__ Wc2, const float* __restrict__ bc2,
    float* __restrict__ out)
{
    // 16-row buffers; rows 8-15 zeroed once and never written (they feed the
    // padded half of the MFMA with exact zeros). +8 f16 pad: 144B row stride,
    // 16B aligned, 2-way bank alias only (free per m136).
    __shared__ __align__(16) _Float16 h0s[2][16][72];
    __shared__ __align__(16) _Float16 h1s[2][16][72];
    __shared__ __align__(16) float h1f[8][68];   // final-step h1 (fp32)
    __shared__ float hid[8][32];

    const int tid  = threadIdx.x;
    const int wid  = tid >> 6;        // wave 0..7
    const int w4   = wid & 3;         // gate-column group within the layer
    const bool isL0 = (wid < 4);
    const int lane = tid & 63;
    const int q  = lane >> 4;         // quad 0..3
    const int lr = lane & 15;
    const bool lo8 = (lr < 8);        // valid-batchrow half of the lane space
    const int br = lr & 7;            // batch row this lane's cells belong to
    const int b0 = blockIdx.x * 8;

    // ---- persistent weight fragments, A-operand layout ----
    // Wave w4 owns gate-col tiles gc_base = (w4+4g)*16, g in {i,f,g,o}.
    // A-frag: lane holds W[gc_base+lr][8q..8q+8)  (identical register content
    // to the r3 B-frags; only the mfma operand order changes).
    // D[m=gc_base+4q+r][n=batchrow=lr]  =>  bias varies with r: float4 init.
    half8 wb[4][4];
    floatx4 binit[4];
    if (isL0) {
        #pragma unroll
        for (int g = 0; g < 4; ++g) {
            int n = (w4 + 4 * g) * 16 + lr;
            wb[g][0] = load_w_frag(Wih0, n, 32, q * 8);
            wb[g][1] = load_w_frag(Whh0, n, 64, q * 8);
            wb[g][2] = load_w_frag(Whh0, n, 64, 32 + q * 8);
            int nb = (w4 + 4 * g) * 16 + 4 * q;
            float4 ba = *(const float4*)&bih0[nb];
            float4 bb = *(const float4*)&bhh0[nb];
            binit[g] = floatx4{ba.x + bb.x, ba.y + bb.y, ba.z + bb.z, ba.w + bb.w};
        }
    } else {
        #pragma unroll
        for (int g = 0; g < 4; ++g) {
            int n = (w4 + 4 * g) * 16 + lr;
            wb[g][0] = load_w_frag(Wih1, n, 64, q * 8);
            wb[g][1] = load_w_frag(Wih1, n, 64, 32 + q * 8);
            wb[g][2] = load_w_frag(Whh1, n, 64, q * 8);
            wb[g][3] = load_w_frag(Whh1, n, 64, 32 + q * 8);
            int nb = (w4 + 4 * g) * 16 + 4 * q;
            float4 ba = *(const float4*)&bih1[nb];
            float4 bb = *(const float4*)&bhh1[nb];
            binit[g] = floatx4{ba.x + bb.x, ba.y + bb.y, ba.z + bb.z, ba.w + bb.w};
        }
    }

    // zero-init both h-state buffers fully (incl. padded rows 8-15)
    for (int i = tid; i < 2 * 16 * 72; i += 512) {
        ((_Float16*)h0s)[i] = (_Float16)0.0f;
        ((_Float16*)h1s)[i] = (_Float16)0.0f;
    }

    float cr[2] = {0.f, 0.f};         // c for this lane's 2 cells

    // Cell->lane map after redistribution: lane (q,lr) owns cells
    // (batchrow=br, units u0,u0+1), u0 = w4*16 + 4q + (lo8 ? 0 : 2).
    const int u0 = w4 * 16 + 4 * q + (lo8 ? 0 : 2);

    // ---- direct global->reg x B-frags (L0 waves), 2-step lookahead ----
    // B-frag: lane needs x[b0+lr][t][8q..8q+8); rows 8-15 are padding -> read
    // the partner row (lr&7) to stay in-bounds (result discarded in D cols>=8).
    const float* xlane = x + ((size_t)(b0 + br) * TT) * 32 + q * 8;
    half8 xcur; float4 xra, xrb;
    if (isL0) {
        float4 a0 = *(const float4*)(xlane);
        float4 a1 = *(const float4*)(xlane + 4);
        xcur = cvt_frag(a0, a1);                       // x(0)
        xra = *(const float4*)(xlane + 32);            // x(1)
        xrb = *(const float4*)(xlane + 36);
    }

    // Iteration k: waves 0-3 compute h0(k) (k < TT); waves 4-7 compute h1(k-1)
    // (k >= 1). h*(k) -> buf[k&1]; h*(k-1) read from buf[(k+1)&1]. Single
    // lgkm-only barrier per iter (double-buffered WAR-safe).
    #pragma unroll 2
    for (int k = 0; k <= TT; ++k) {
        bar_lds();

        const int rd = (k + 1) & 1;
        const int wr = k & 1;
        const bool doL0 = isL0 && (k < TT);
        const bool doL1 = (!isL0) && (k >= 1);
        floatx4 a[4];

        if (doL0) {
            // gates^T = bias + Wih0 x(k)^T + Whh0 h0(k-1)^T
            half8 hb0a = *(const half8*)&h0s[rd][lr][q * 8];
            half8 hb0b = *(const half8*)&h0s[rd][lr][32 + q * 8];
            half8 xnxt = cvt_frag(xra, xrb);
            int t2 = (k + 2 < TT) ? (k + 2) : (TT - 1);
            xra = *(const float4*)(xlane + (size_t)t2 * 32);
            xrb = *(const float4*)(xlane + (size_t)t2 * 32 + 4);
            #pragma unroll
            for (int g = 0; g < 4; ++g) {
                floatx4 acc = binit[g];
                acc = __builtin_amdgcn_mfma_f32_16x16x32_f16(wb[g][0], xcur, acc, 0, 0, 0);
                acc = __builtin_amdgcn_mfma_f32_16x16x32_f16(wb[g][1], hb0a, acc, 0, 0, 0);
                acc = __builtin_amdgcn_mfma_f32_16x16x32_f16(wb[g][2], hb0b, acc, 0, 0, 0);
                a[g] = acc;
            }
            xcur = xnxt;
        }
        if (doL1) {
            // gates^T = bias + Wih1 h0(k-1)^T + Whh1 h1(k-2)^T
            half8 g0a = *(const half8*)&h0s[rd][lr][q * 8];
            half8 g0b = *(const half8*)&h0s[rd][lr][32 + q * 8];
            half8 h1a = *(const half8*)&h1s[rd][lr][q * 8];
            half8 h1b = *(const half8*)&h1s[rd][lr][32 + q * 8];
            #pragma unroll
            for (int g = 0; g < 4; ++g) {
                floatx4 acc = binit[g];
                acc = __builtin_amdgcn_mfma_f32_16x16x32_f16(wb[g][0], g0a, acc, 0, 0, 0);
                acc = __builtin_amdgcn_mfma_f32_16x16x32_f16(wb[g][1], g0b, acc, 0, 0, 0);
                acc = __builtin_amdgcn_mfma_f32_16x16x32_f16(wb[g][2], h1a, acc, 0, 0, 0);
                acc = __builtin_amdgcn_mfma_f32_16x16x32_f16(wb[g][3], h1b, acc, 0, 0, 0);
                a[g] = acc;
            }
        }

        if (doL0 || doL1) {
            // Redistribute: lanes lr>=8 take cells r in {2,3} from lane^8.
            float v0[4], v1[4];
            #pragma unroll
            for (int g = 0; g < 4; ++g) {
                float s2 = swz8(a[g][2]);
                float s3 = swz8(a[g][3]);
                v0[g] = lo8 ? a[g][0] : s2;
                v1[g] = lo8 ? a[g][1] : s3;
            }
            float hv0, hv1;
            cell_update(v0[0], v0[1], v0[2], v0[3], cr[0], hv0);
            cell_update(v1[0], v1[1], v1[2], v1[3], cr[1], hv1);

            if (doL0) {
                *(half2v*)&h0s[wr][br][u0] = pk16(hv0, hv1);
            } else if (k == TT) {
                *(float2*)&h1f[br][u0] = float2{hv0, hv1};
            } else {
                *(half2v*)&h1s[wr][br][u0] = pk16(hv0, hv1);
            }
        }
    }
    __syncthreads();   // full drain once, outside the hot loop

    // ---- classifier (fp32): hidden = relu(hT Wc1^T + bc1); out = hidden Wc2^T + bc2
    if (tid < 256) {
        int m = tid >> 5;             // 8 rows
        int u = tid & 31;             // 32 hidden units
        float acc = bc1[u];
        const float* w0 = Wc1 + u * 64;
        #pragma unroll 8
        for (int kk = 0; kk < 64; ++kk)
            acc += h1f[m][kk] * w0[kk];
        hid[m][u] = fmaxf(acc, 0.f);
    }
    __syncthreads();
    if (tid < 8) {
        float o = bc2[0];
        #pragma unroll
        for (int u = 0; u < 32; ++u) o += hid[tid][u] * Wc2[u];
        out[b0 + tid] = o;
    }
}

extern "C" void kernel_launch(void* const* d_in, const int* in_sizes, int n_in,
                              void* d_out, int out_size, void* d_ws, size_t ws_size,
                              hipStream_t stream) {
    (void)in_sizes; (void)n_in; (void)d_ws; (void)ws_size; (void)out_size;
    const float* x    = (const float*)d_in[0];
    const float* Wih0 = (const float*)d_in[1];
    const float* Whh0 = (const float*)d_in[2];
    const float* bih0 = (const float*)d_in[3];
    const float* bhh0 = (const float*)d_in[4];
    const float* Wih1 = (const float*)d_in[5];
    const float* Whh1 = (const float*)d_in[6];
    const float* bih1 = (const float*)d_in[7];
    const float* bhh1 = (const float*)d_in[8];
    const float* Wc1  = (const float*)d_in[9];
    const float* bc1  = (const float*)d_in[10];
    const float* Wc2  = (const float*)d_in[11];
    const float* bc2  = (const float*)d_in[12];
    lstm_fused<<<dim3(512), dim3(512), 0, stream>>>(
        x, Wih0, Whh0, bih0, bhh0, Wih1, Whh1, bih1, bhh1, Wc1, bc1, Wc2, bc2,
        (float*)d_out);
}